// Round 9
// baseline (361.979 us; speedup 1.0000x reference)
//
#include <hip/hip_runtime.h>
#include <hip/hip_bf16.h>

#define NTOK 16384
#define HID 7168
#define NEXP 256
#define TOPK 8

#define BT 64                  // tokens per block
#define BK 64                  // k per chunk
#define NCH (HID / BK)         // 112 (even)

typedef __bf16 bf16x8 __attribute__((ext_vector_type(8)));
typedef float  f32x16 __attribute__((ext_vector_type(16)));

// RTNE f32 -> bf16 bits
__device__ __forceinline__ unsigned int f2bfb(float x) {
    unsigned int u = __float_as_uint(x);
    return (u + 0x7fffu + ((u >> 16) & 1u)) >> 16;
}
__device__ __forceinline__ bf16x8 asbf8(uint4 u) {
    union { uint4 a; bf16x8 b; } c; c.a = u; return c.b;
}
// pack 8 f32 -> 8 bf16 (function, not macro: avoids param/member token capture)
__device__ __forceinline__ uint4 pk4(float4 p, float4 q) {
    uint4 u;
    u.x = f2bfb(p.x) | (f2bfb(p.y) << 16);
    u.y = f2bfb(p.z) | (f2bfb(p.w) << 16);
    u.z = f2bfb(q.x) | (f2bfb(q.y) << 16);
    u.w = f2bfb(q.z) | (f2bfb(q.w) << 16);
    return u;
}

// ---- pre-convert weight f32 -> bf16 into workspace (3.67 MB) ----
__global__ void wconv(const float* __restrict__ wt, unsigned short* __restrict__ wb) {
    const int i = blockIdx.x * 256 + threadIdx.x;
    const float4 v = ((const float4*)wt)[i];
    uint2 o;
    o.x = f2bfb(v.x) | (f2bfb(v.y) << 16);
    o.y = f2bfb(v.z) | (f2bfb(v.w) << 16);
    ((uint2*)wb)[i] = o;
}

// row_idx: row[t][k] = k*NTOK + t (chunk 2)
__global__ void moe_rows(float* __restrict__ ob) {
    const int q = blockIdx.x * 256 + threadIdx.x;
    ob[262144 + q] = (float)((q & 7) * NTOK + (q >> 3));
}

// LDS: lbuf0 @0 (8 KB), lbuf1 @8192 (8 KB); epilogue aliases [64][257] f32 (65.8 KB)
template<bool PRECONV>
__global__ __launch_bounds__(512) void moe_gate_v8(
    const float* __restrict__ hs,
    const float* __restrict__ wt,
    const unsigned short* __restrict__ wb,
    float* __restrict__ ob)
{
    __shared__ __align__(16) char smem[66560];
    char* const lbuf0 = smem;
    char* const lbuf1 = smem + 8192;

    const int tid  = threadIdx.x;
    const int t0   = blockIdx.x * BT;
    const int lane = tid & 63;
    const int wv   = tid >> 6;        // 0..7
    const int wm   = wv >> 2;         // token half
    const int wn   = wv & 3;          // expert quarter (64 experts)

    // ---- A staging map: thread -> (token row, 8 consecutive f32) ----
    const int tr = tid >> 3;                      // 0..63
    const int kg = tid & 7;                       // 0..7
    const float* apt = hs + (size_t)(t0 + tr) * HID + kg * 8;
    const int aofs = (tr * 128 + kg * 16) ^ ((tr & 7) << 4);

    // ---- fragment read offsets (A from LDS) ----
    const int kl  = (lane >> 5) * 16;
    const int swz = (lane & 7) << 4;
    const int frA = (wm * 32 + (lane & 31)) * 128;

    // ---- B per-lane global base (expert e0 / e0+32, k-half by lane>>5) ----
    const int e0 = wn * 64 + (lane & 31);
    const unsigned short* bb0 = nullptr;
    const float* fb0 = nullptr;
    if constexpr (PRECONV) bb0 = wb + (size_t)e0 * HID + (lane >> 5) * 8;
    else                   fb0 = wt + (size_t)e0 * HID + (lane >> 5) * 8;

    f32x16 acc0 = {};   // experts e0
    f32x16 acc1 = {};   // experts e0+32

    float4 fa00, fa01, fa10, fa11;                 // A reg sets (2 x 2 float4)
    uint4 b00, b01, b02, b03, b04, b05, b06, b07;  // B set 0 (et0 kk0..3, et1 kk0..3)
    uint4 b10, b11, b12, b13, b14, b15, b16, b17;  // B set 1

#define LOADA(S, sidx)                                                        \
    do {                                                                      \
        fa##S##0 = *(const float4*)(apt + (size_t)(sidx) * BK);               \
        fa##S##1 = *(const float4*)(apt + (size_t)(sidx) * BK + 4);           \
    } while (0)

#define LOADB(S, sidx)                                                        \
    do {                                                                      \
        if constexpr (PRECONV) {                                              \
            const unsigned short* p0 = bb0 + (size_t)(sidx) * BK;             \
            const unsigned short* p1 = p0 + (size_t)32 * HID;                 \
            b##S##0 = *(const uint4*)(p0);                                    \
            b##S##1 = *(const uint4*)(p0 + 16);                               \
            b##S##2 = *(const uint4*)(p0 + 32);                               \
            b##S##3 = *(const uint4*)(p0 + 48);                               \
            b##S##4 = *(const uint4*)(p1);                                    \
            b##S##5 = *(const uint4*)(p1 + 16);                               \
            b##S##6 = *(const uint4*)(p1 + 32);                               \
            b##S##7 = *(const uint4*)(p1 + 48);                               \
        } else {                                                              \
            const float* q0 = fb0 + (size_t)(sidx) * BK;                      \
            const float* q1 = q0 + (size_t)32 * HID;                          \
            b##S##0 = pk4(*(const float4*)(q0),      *(const float4*)(q0 + 4));  \
            b##S##1 = pk4(*(const float4*)(q0 + 16), *(const float4*)(q0 + 20)); \
            b##S##2 = pk4(*(const float4*)(q0 + 32), *(const float4*)(q0 + 36)); \
            b##S##3 = pk4(*(const float4*)(q0 + 48), *(const float4*)(q0 + 52)); \
            b##S##4 = pk4(*(const float4*)(q1),      *(const float4*)(q1 + 4));  \
            b##S##5 = pk4(*(const float4*)(q1 + 16), *(const float4*)(q1 + 20)); \
            b##S##6 = pk4(*(const float4*)(q1 + 32), *(const float4*)(q1 + 36)); \
            b##S##7 = pk4(*(const float4*)(q1 + 48), *(const float4*)(q1 + 52)); \
        }                                                                     \
    } while (0)

#define WRITEA(S, LB)                                                         \
    do {                                                                      \
        *(uint4*)((LB) + aofs) = pk4(fa##S##0, fa##S##1);                     \
    } while (0)

#define COMPUTE(S, LB)                                                        \
    do {                                                                      \
        bf16x8 a;                                                             \
        a = *(const bf16x8*)((LB) + frA + ((0 * 32 + kl) ^ swz));             \
        acc0 = __builtin_amdgcn_mfma_f32_32x32x16_bf16(a, asbf8(b##S##0), acc0, 0, 0, 0); \
        acc1 = __builtin_amdgcn_mfma_f32_32x32x16_bf16(a, asbf8(b##S##4), acc1, 0, 0, 0); \
        a = *(const bf16x8*)((LB) + frA + ((1 * 32 + kl) ^ swz));             \
        acc0 = __builtin_amdgcn_mfma_f32_32x32x16_bf16(a, asbf8(b##S##1), acc0, 0, 0, 0); \
        acc1 = __builtin_amdgcn_mfma_f32_32x32x16_bf16(a, asbf8(b##S##5), acc1, 0, 0, 0); \
        a = *(const bf16x8*)((LB) + frA + ((2 * 32 + kl) ^ swz));             \
        acc0 = __builtin_amdgcn_mfma_f32_32x32x16_bf16(a, asbf8(b##S##2), acc0, 0, 0, 0); \
        acc1 = __builtin_amdgcn_mfma_f32_32x32x16_bf16(a, asbf8(b##S##6), acc1, 0, 0, 0); \
        a = *(const bf16x8*)((LB) + frA + ((3 * 32 + kl) ^ swz));             \
        acc0 = __builtin_amdgcn_mfma_f32_32x32x16_bf16(a, asbf8(b##S##3), acc0, 0, 0, 0); \
        acc1 = __builtin_amdgcn_mfma_f32_32x32x16_bf16(a, asbf8(b##S##7), acc1, 0, 0, 0); \
    } while (0)

#define SOFTBAR()                                                             \
    do {                                                                      \
        asm volatile("s_waitcnt lgkmcnt(0)" ::: "memory");                    \
        __builtin_amdgcn_s_barrier();                                         \
    } while (0)

    // ---- prologue ----
    LOADA(0, 0); LOADA(1, 1); LOADB(0, 0);
    WRITEA(0, lbuf0);              // waits A0 loads only (oldest in FIFO)
    SOFTBAR();                     // B0 stays in flight

    // ---- main loop: x2 unrolled, raw barriers (no vmcnt drain) ----
    for (int s = 0; s < NCH; s += 2) {
        // even chunk s: A from lbuf0, B set0
        if (s + 2 < NCH) LOADA(0, s + 2);
        LOADB(1, s + 1);
        COMPUTE(0, lbuf0);
        WRITEA(1, lbuf1);          // chunk s+1 (loaded one chunk ago)
        SOFTBAR();

        // odd chunk s+1: A from lbuf1, B set1
        if (s + 3 < NCH) LOADA(1, s + 3);
        if (s + 2 < NCH) LOADB(0, s + 2);
        COMPUTE(1, lbuf1);
        if (s + 2 < NCH) {
            WRITEA(0, lbuf0);      // chunk s+2
            SOFTBAR();
        }
    }
    __syncthreads();               // full drain before aliasing smem

    // ---- epilogue: dump logits to LDS [64][257] f32 ----
    float* ll = (float*)smem;
    {
        const int ec = wn * 64 + (lane & 31);
        const int rb = wm * 32 + 4 * (lane >> 5);
        #pragma unroll
        for (int r = 0; r < 16; ++r) {
            const int tok = rb + (r & 3) + 8 * (r >> 2);
            ll[tok * 257 + ec]      = acc0[r];
            ll[tok * 257 + ec + 32] = acc1[r];
        }
    }
    __syncthreads();

    if (tid < BT) {
        const float* lr = ll + tid * 257;
        float bv[TOPK]; int bi8[TOPK];
        #pragma unroll
        for (int k = 0; k < TOPK; ++k) { bv[k] = -1e30f; bi8[k] = 0; }
        for (int e = 0; e < NEXP; ++e) {
            const float v = lr[e];
            if (v > bv[TOPK - 1]) {
                int k = TOPK - 1;
                while (k > 0 && v > bv[k - 1]) {
                    bv[k] = bv[k - 1]; bi8[k] = bi8[k - 1]; --k;
                }
                bv[k] = v; bi8[k] = e;          // strict > : ties keep lower idx
            }
        }
        float ev[TOPK], ssum = 0.f;
        #pragma unroll
        for (int r = 0; r < TOPK; ++r) { ev[r] = expf(bv[r] - bv[0]); ssum += ev[r]; }
        const float inv = 1.0f / ssum;

        const int tg = t0 + tid;
        #pragma unroll
        for (int r = 0; r < TOPK; ++r) {
            ob[(size_t)tg * TOPK + r]          = (float)bi8[r];   // chunk 0: idx
            ob[131072 + (size_t)tg * TOPK + r] = ev[r] * inv;     // chunk 1: weight
        }
    }
#undef LOADA
#undef LOADB
#undef WRITEA
#undef COMPUTE
#undef SOFTBAR
}

extern "C" void kernel_launch(void* const* d_in, const int* in_sizes, int n_in,
                              void* d_out, int out_size, void* d_ws, size_t ws_size,
                              hipStream_t stream) {
    const float* hs = (const float*)d_in[0];   // [16384, 7168] f32
    const float* wt = (const float*)d_in[1];   // [256, 7168] f32
    float* ob = (float*)d_out;                 // f32[393216]: idx | weight | row

    if (ws_size >= (size_t)NEXP * HID * 2) {
        unsigned short* wb = (unsigned short*)d_ws;
        wconv<<<dim3(NEXP * HID / 4 / 256), dim3(256), 0, stream>>>(wt, wb);
        moe_gate_v8<true><<<dim3(NTOK / BT), dim3(512), 0, stream>>>(hs, wt, wb, ob);
    } else {
        moe_gate_v8<false><<<dim3(NTOK / BT), dim3(512), 0, stream>>>(hs, wt, nullptr, ob);
    }
    moe_rows<<<dim3(512), dim3(256), 0, stream>>>(ob);
}

// Round 10
// 244.199 us; speedup vs baseline: 1.4823x; 1.4823x over previous
//
#include <hip/hip_runtime.h>
#include <hip/hip_bf16.h>

#define NTOK 16384
#define HID 7168
#define NEXP 256
#define TOPK 8

#define BT 64                  // tokens per block
#define BK 64                  // k per chunk
#define NCH (HID / BK)         // 112 (even)

typedef __bf16 bf16x8 __attribute__((ext_vector_type(8)));
typedef float  f32x16 __attribute__((ext_vector_type(16)));

// RTNE f32 -> bf16 bits
__device__ __forceinline__ unsigned int f2bfb(float x) {
    unsigned int u = __float_as_uint(x);
    return (u + 0x7fffu + ((u >> 16) & 1u)) >> 16;
}
__device__ __forceinline__ bf16x8 asbf8(uint4 u) {
    union { uint4 a; bf16x8 b; } c; c.a = u; return c.b;
}
// pack 8 f32 -> 8 bf16 (function, not macro: no token capture)
__device__ __forceinline__ uint4 pk4(float4 p, float4 q) {
    uint4 u;
    u.x = f2bfb(p.x) | (f2bfb(p.y) << 16);
    u.y = f2bfb(p.z) | (f2bfb(p.w) << 16);
    u.z = f2bfb(q.x) | (f2bfb(q.y) << 16);
    u.w = f2bfb(q.z) | (f2bfb(q.w) << 16);
    return u;
}

// ---- pre-convert weight f32 -> bf16 into workspace (3.67 MB) ----
__global__ void wconv(const float* __restrict__ wt, unsigned short* __restrict__ wb) {
    const int i = blockIdx.x * 256 + threadIdx.x;
    const float4 v = ((const float4*)wt)[i];
    uint2 o;
    o.x = f2bfb(v.x) | (f2bfb(v.y) << 16);
    o.y = f2bfb(v.z) | (f2bfb(v.w) << 16);
    ((uint2*)wb)[i] = o;
}

// row_idx: row[t][k] = k*NTOK + t (chunk 2)
__global__ void moe_rows(float* __restrict__ ob) {
    const int q = blockIdx.x * 256 + threadIdx.x;
    ob[262144 + q] = (float)((q & 7) * NTOK + (q >> 3));
}

// LDS: bufA0 @0 (8K) bufA1 @8192 (8K) bufB0 @16384 (32K) bufB1 @49152 (32K) = 80 KB
// epilogue aliases logits [64][257] f32 (65.8 KB)
template<bool PRECONV>
__global__ __launch_bounds__(512) void moe_gate_v10(
    const float* __restrict__ hs,
    const float* __restrict__ wt,
    const unsigned short* __restrict__ wb,
    float* __restrict__ ob)
{
    __shared__ __align__(16) char smem[81920];
    char* const bufA0 = smem;
    char* const bufA1 = smem + 8192;
    char* const bufB0 = smem + 16384;
    char* const bufB1 = smem + 49152;

    const int tid  = threadIdx.x;
    const int t0   = blockIdx.x * BT;
    const int lane = tid & 63;
    const int wv   = tid >> 6;        // 0..7
    const int wm   = wv >> 2;         // token half
    const int wn   = wv & 3;          // expert quarter (64 experts)

    // ---- A staging map: thread -> (token row, 8 consecutive f32 -> 8 bf16) ----
    const int tr = tid >> 3;                      // 0..63
    const int kg = tid & 7;                       // 0..7
    const float* apt = hs + (size_t)(t0 + tr) * HID + kg * 8;
    const int aofs = (tr * 128 + kg * 16) ^ ((tr & 7) << 4);

    // ---- B staging map: 2048 items (exp 0..255 x 8 kgroups of 16 B), 4/thread ----
    const int brow = tid >> 3;                    // 0..63 (+64,+128,+192)
    const int bkg  = tid & 7;
    const unsigned short* bpt = PRECONV ? (wb + (size_t)brow * HID + bkg * 8) : (const unsigned short*)0;
    const float* fpt = wt + (size_t)brow * HID + bkg * 8;
    const int bsw  = ((brow & 7) << 4);
    const int bofs0 = ((brow      ) * 128 + bkg * 16) ^ bsw;
    const int bofs1 = ((brow +  64) * 128 + bkg * 16) ^ bsw;
    const int bofs2 = ((brow + 128) * 128 + bkg * 16) ^ bsw;
    const int bofs3 = ((brow + 192) * 128 + bkg * 16) ^ bsw;

    // ---- fragment read offsets ----
    const int kl  = (lane >> 5) * 16;
    const int swz = (lane & 7) << 4;
    const int frA = (wm * 32 + (lane & 31)) * 128;
    const int erB0 = (wn * 64 + (lane & 31)) * 128;
    const int erB1 = erB0 + 32 * 128;

    f32x16 acc0 = {};   // experts e0
    f32x16 acc1 = {};   // experts e0+32

    float4 fa00, fa01, fa10, fa11;                 // A reg sets
    uint4  rb00, rb01, rb02, rb03;                 // B set 0 (bf16 path)
    uint4  rb10, rb11, rb12, rb13;                 // B set 1
    float4 rf00, rf01, rf02, rf03, rf04, rf05, rf06, rf07;  // B set 0 (f32 path)
    float4 rf10, rf11, rf12, rf13, rf14, rf15, rf16, rf17;  // B set 1

#define LOADA(S, sidx)                                                        \
    do {                                                                      \
        fa##S##0 = *(const float4*)(apt + (size_t)(sidx) * BK);               \
        fa##S##1 = *(const float4*)(apt + (size_t)(sidx) * BK + 4);           \
    } while (0)

#define LOADB(S, sidx)                                                        \
    do {                                                                      \
        if constexpr (PRECONV) {                                              \
            rb##S##0 = *(const uint4*)(bpt + (size_t)(sidx) * BK);            \
            rb##S##1 = *(const uint4*)(bpt + (size_t)64  * HID + (size_t)(sidx) * BK); \
            rb##S##2 = *(const uint4*)(bpt + (size_t)128 * HID + (size_t)(sidx) * BK); \
            rb##S##3 = *(const uint4*)(bpt + (size_t)192 * HID + (size_t)(sidx) * BK); \
        } else {                                                              \
            const float* p = fpt + (size_t)(sidx) * BK;                       \
            rf##S##0 = *(const float4*)(p);                                   \
            rf##S##1 = *(const float4*)(p + 4);                               \
            rf##S##2 = *(const float4*)(p + (size_t)64 * HID);                \
            rf##S##3 = *(const float4*)(p + (size_t)64 * HID + 4);            \
            rf##S##4 = *(const float4*)(p + (size_t)128 * HID);               \
            rf##S##5 = *(const float4*)(p + (size_t)128 * HID + 4);           \
            rf##S##6 = *(const float4*)(p + (size_t)192 * HID);               \
            rf##S##7 = *(const float4*)(p + (size_t)192 * HID + 4);           \
        }                                                                     \
    } while (0)

#define WRITEA(S, LB)                                                         \
    do {                                                                      \
        *(uint4*)((LB) + aofs) = pk4(fa##S##0, fa##S##1);                     \
    } while (0)

#define WRITEB(S, LB)                                                         \
    do {                                                                      \
        if constexpr (PRECONV) {                                              \
            *(uint4*)((LB) + bofs0) = rb##S##0;                               \
            *(uint4*)((LB) + bofs1) = rb##S##1;                               \
            *(uint4*)((LB) + bofs2) = rb##S##2;                               \
            *(uint4*)((LB) + bofs3) = rb##S##3;                               \
        } else {                                                              \
            *(uint4*)((LB) + bofs0) = pk4(rf##S##0, rf##S##1);                \
            *(uint4*)((LB) + bofs1) = pk4(rf##S##2, rf##S##3);                \
            *(uint4*)((LB) + bofs2) = pk4(rf##S##4, rf##S##5);                \
            *(uint4*)((LB) + bofs3) = pk4(rf##S##6, rf##S##7);                \
        }                                                                     \
    } while (0)

#define COMPUTE(LA, LB)                                                       \
    do {                                                                      \
        _Pragma("unroll")                                                     \
        for (int kk = 0; kk < 4; ++kk) {                                      \
            const int c = (kk * 32 + kl) ^ swz;                               \
            bf16x8 a  = *(const bf16x8*)((LA) + frA  + c);                    \
            bf16x8 b0 = *(const bf16x8*)((LB) + erB0 + c);                    \
            bf16x8 b1 = *(const bf16x8*)((LB) + erB1 + c);                    \
            acc0 = __builtin_amdgcn_mfma_f32_32x32x16_bf16(a, b0, acc0, 0, 0, 0); \
            acc1 = __builtin_amdgcn_mfma_f32_32x32x16_bf16(a, b1, acc1, 0, 0, 0); \
        }                                                                     \
    } while (0)

    // lgkm-only barrier: ds ops visible, global loads stay in flight (no vmcnt drain)
#define SOFTBAR()                                                             \
    do {                                                                      \
        asm volatile("s_waitcnt lgkmcnt(0)" ::: "memory");                    \
        __builtin_amdgcn_s_barrier();                                         \
    } while (0)

    // ---- prologue: stage chunk 0; chunk 1 loads stay in flight ----
    LOADA(0, 0); LOADB(0, 0);
    LOADA(1, 1); LOADB(1, 1);
    WRITEA(0, bufA0); WRITEB(0, bufB0);   // compiler: counted vmcnt for set0 only
    SOFTBAR();

    // ---- main loop: x2 unrolled, depth-2 pipeline ----
    for (int s = 0; s < NCH; s += 2) {
        // even chunk s from buf0
        if (s + 2 < NCH) { LOADA(0, s + 2); LOADB(0, s + 2); }
        COMPUTE(bufA0, bufB0);
        WRITEA(1, bufA1); WRITEB(1, bufB1);       // chunk s+1 (in flight 1 iter)
        SOFTBAR();

        // odd chunk s+1 from buf1
        if (s + 3 < NCH) { LOADA(1, s + 3); LOADB(1, s + 3); }
        COMPUTE(bufA1, bufB1);
        if (s + 2 < NCH) {
            WRITEA(0, bufA0); WRITEB(0, bufB0);   // chunk s+2
            SOFTBAR();
        }
    }
    __syncthreads();               // full drain once before aliasing smem

    // ---- epilogue: dump logits to LDS [64][257] f32 ----
    float* ll = (float*)smem;
    {
        const int ec = wn * 64 + (lane & 31);
        const int rb = wm * 32 + 4 * (lane >> 5);
        #pragma unroll
        for (int r = 0; r < 16; ++r) {
            const int tok = rb + (r & 3) + 8 * (r >> 2);
            ll[tok * 257 + ec]      = acc0[r];
            ll[tok * 257 + ec + 32] = acc1[r];
        }
    }
    __syncthreads();

    if (tid < BT) {
        const float* lr = ll + tid * 257;
        float bv[TOPK]; int bi8[TOPK];
        #pragma unroll
        for (int k = 0; k < TOPK; ++k) { bv[k] = -1e30f; bi8[k] = 0; }
        for (int e = 0; e < NEXP; ++e) {
            const float v = lr[e];
            if (v > bv[TOPK - 1]) {
                int k = TOPK - 1;
                while (k > 0 && v > bv[k - 1]) {
                    bv[k] = bv[k - 1]; bi8[k] = bi8[k - 1]; --k;
                }
                bv[k] = v; bi8[k] = e;          // strict > : ties keep lower idx
            }
        }
        float ev[TOPK], ssum = 0.f;
        #pragma unroll
        for (int r = 0; r < TOPK; ++r) { ev[r] = expf(bv[r] - bv[0]); ssum += ev[r]; }
        const float inv = 1.0f / ssum;

        const int tg = t0 + tid;
        #pragma unroll
        for (int r = 0; r < TOPK; ++r) {
            ob[(size_t)tg * TOPK + r]          = (float)bi8[r];   // chunk 0: idx
            ob[131072 + (size_t)tg * TOPK + r] = ev[r] * inv;     // chunk 1: weight
        }
    }
#undef LOADA
#undef LOADB
#undef WRITEA
#undef WRITEB
#undef COMPUTE
#undef SOFTBAR
}

extern "C" void kernel_launch(void* const* d_in, const int* in_sizes, int n_in,
                              void* d_out, int out_size, void* d_ws, size_t ws_size,
                              hipStream_t stream) {
    const float* hs = (const float*)d_in[0];   // [16384, 7168] f32
    const float* wt = (const float*)d_in[1];   // [256, 7168] f32
    float* ob = (float*)d_out;                 // f32[393216]: idx | weight | row

    if (ws_size >= (size_t)NEXP * HID * 2) {
        unsigned short* wb = (unsigned short*)d_ws;
        wconv<<<dim3(NEXP * HID / 4 / 256), dim3(256), 0, stream>>>(wt, wb);
        moe_gate_v10<true><<<dim3(NTOK / BT), dim3(512), 0, stream>>>(hs, wt, wb, ob);
    } else {
        moe_gate_v10<false><<<dim3(NTOK / BT), dim3(512), 0, stream>>>(hs, wt, nullptr, ob);
    }
    moe_rows<<<dim3(512), dim3(256), 0, stream>>>(ob);
}